// Round 15
// baseline (159.938 us; speedup 1.0000x reference)
//
#include <hip/hip_runtime.h>

#define HEADS 8
#define DH 64
#define CO 3
#define E 192
#define NSEQ 2048
#define BATCH 2
#define CIN 256
#define DINNER 512
#define NTOK 4096
#define BHTOT 16

typedef __attribute__((ext_vector_type(8))) short bf16x8;
typedef __attribute__((ext_vector_type(4))) short bf16x4;
typedef __attribute__((ext_vector_type(4))) float f32x4;
typedef __attribute__((ext_vector_type(4))) float float4v;

static __device__ inline short f2bf(float f) {
  union { float f; unsigned u; } v; v.f = f;
  unsigned r = (v.u + 0x7FFFu + ((v.u >> 16) & 1u)) >> 16;  // RNE
  return (short)r;
}

static __device__ inline float bf2f(short s) {
  union { unsigned u; float f; } a;
  a.u = ((unsigned)(unsigned short)s) << 16;
  return a.f;
}

static __device__ inline void load_lds16(const short* g, short* l) {
  __builtin_amdgcn_global_load_lds(
      (const __attribute__((address_space(1))) void*)g,
      (__attribute__((address_space(3))) void*)l, 16, 0, 0);
}

// Frag-tile packing: a 16(row)x32(k) bf16 MFMA operand tile = 512 shorts,
// element [row r][k = qd*8+j] at (qd*16 + r)*8 + j (consuming wave's lane order).
// Internal e-order: e = c*64 + d.

// ---------------------------------------------------------------- prep
__global__ __launch_bounds__(256) void prep(const float* __restrict__ x,
                                            const float* __restrict__ Wq,
                                            const float* __restrict__ Wk,
                                            const float* __restrict__ Wv,
                                            const float* __restrict__ Wo,
                                            short* __restrict__ xcp,
                                            short* __restrict__ wqkvp,
                                            short* __restrict__ wop) {
  int tid = threadIdx.x;
  if (blockIdx.x < 256) {
    __shared__ short st[12288];  // [c][ks][512]
    int mt = blockIdx.x;
    const float* xb = x + (size_t)mt * 12288;
#pragma unroll
    for (int r = 0; r < 12; r++) {
      int idx4 = r * 256 + tid;
      float4v v = *(const float4v*)(xb + idx4 * 4);
#pragma unroll
      for (int e = 0; e < 4; e++) {
        int fp = idx4 * 4 + e;
        int ti = fp / 3, c = fp - ti * 3;
        int tl = ti >> 8, i = ti & 255;
        int ks = i >> 5, qd = (i >> 3) & 3, j = i & 7;
        st[c * 4096 + ks * 512 + (qd * 16 + tl) * 8 + j] = f2bf(v[e]);
      }
    }
    __syncthreads();
    short* dst = xcp;
#pragma unroll
    for (int rep = 0; rep < 6; rep++) {
      int g = rep * 256 + tid;
      int c = g >> 9, rem = g & 511;
      *(bf16x8*)(dst + ((size_t)(c * 256 + mt) * 8) * 512 + rem * 8) =
          *(const bf16x8*)&st[c * 4096 + rem * 8];
    }
    return;
  }
  int idx = (blockIdx.x - 256) * 256 + tid;
  const float qscale = 0.07216878364870323f * 1.4426950408889634f;  // 192^-0.5 * log2(e)
  if (idx < 1536 * 256) {
    int o = idx >> 8, i = idx & 255;
    float v;
    if (o < 512) v = Wq[idx] * qscale;
    else if (o < 1024) v = Wk[idx - 512 * 256];
    else v = Wv[idx - 1024 * 256];
    int nt = o >> 4, ln = o & 15, ks = i >> 5, qd = (i >> 3) & 3, j = i & 7;
    wqkvp[((size_t)(nt * 8 + ks)) * 512 + (qd * 16 + ln) * 8 + j] = f2bf(v);
  } else {
    int j0 = idx - 1536 * 256;
    if (j0 < 256 * 512) {
      int o2 = j0 >> 9, i = j0 & 511;
      int nt = o2 >> 4, ln = o2 & 15, ks = i >> 5, qd = (i >> 3) & 3, j = i & 7;
      wop[((size_t)(nt * 16 + ks)) * 512 + (qd * 16 + ln) * 8 + j] = f2bf(Wo[j0]);
    }
  }
}

// ---------------------------------------------------------------- qkv_gemm v4
// 128m x 64n tiles, grid (24,32,3). 2-STEP K-UNROLL: 16 KB (two k-steps) per
// dbuf phase -> 5 barriers/block instead of 9. B-frags direct from L2-resident
// wqkvp. LDS 32 KB -> 4 blocks/CU.
__global__ __launch_bounds__(256, 4) void qkv_gemm(const short* __restrict__ xcp,
                                                   const short* __restrict__ wqkvp,
                                                   short* __restrict__ qp,
                                                   short* __restrict__ kp,
                                                   short* __restrict__ vp) {
  __shared__ __align__(16) short pool[16384];  // A dbuf 2x8192 | epilogue tp [128][72]
  int c = blockIdx.z, ntb = blockIdx.x, mtb = blockIdx.y;
  int tid = threadIdx.x, wave = tid >> 6, lane = tid & 63;
  int ln = lane & 15, quad = lane >> 4;
  int wm = wave >> 1, wn = wave & 1;

  const short* gA = xcp + ((size_t)(c * 256 + mtb * 8) * 8) * 512;

  // stage two k-steps (ph*2, ph*2+1) into buffer buf
  auto stage = [&](int ph, int buf) {
#pragma unroll
    for (int i = 0; i < 4; i++) {
      int q = i * 256 + tid;             // 1024 chunks of 8 shorts
      int half = q >> 9, mf = (q >> 6) & 7, l = q & 63;
      load_lds16(gA + (size_t)(mf * 8 + ph * 2 + half) * 512 + l * 8,
                 pool + buf * 8192 + (q & 511) * 8 + half * 4096);
    }
  };

  f32x4 acc[4][2] = {};
  stage(0, 0);
  for (int ph = 0; ph < 4; ph++) {
    int b = ph & 1;
    __syncthreads();
    if (ph < 3) stage(ph + 1, b ^ 1);
#pragma unroll
    for (int half = 0; half < 2; half++) {
      int ks = ph * 2 + half;
      const short* As = pool + b * 8192 + half * 4096;
      bf16x8 af[4], bfr[2];
#pragma unroll
      for (int j = 0; j < 2; j++)
        bfr[j] = *(const bf16x8*)(wqkvp +
            (size_t)((ntb * 4 + wn * 2 + j) * 8 + ks) * 512 + lane * 8);
#pragma unroll
      for (int i = 0; i < 4; i++) af[i] = *(const bf16x8*)&As[(wm * 4 + i) * 512 + lane * 8];
#pragma unroll
      for (int i = 0; i < 4; i++)
#pragma unroll
        for (int j = 0; j < 2; j++)
          acc[i][j] = __builtin_amdgcn_mfma_f32_16x16x32_bf16(af[i], bfr[j], acc[i][j], 0, 0, 0);
    }
  }

  int mat = ntb >> 3;        // 0=Q 1=K 2=V (block-uniform)
  int h = ntb & 7;
  int b0 = mtb >> 4;
  int bhx = b0 * 8 + h;
  if (mat < 2) {
    __syncthreads();
    short* tp = pool;  // [128][72]: 9216 <= 16384
#pragma unroll
    for (int i = 0; i < 4; i++)
#pragma unroll
      for (int j = 0; j < 2; j++)
#pragma unroll
        for (int jj = 0; jj < 4; jj++)
          tp[(wm * 64 + i * 16 + quad * 4 + jj) * 72 + wn * 32 + j * 16 + ln] =
              f2bf(acc[i][j][jj]);
    __syncthreads();
    short* dst = (mat == 0) ? qp : kp;
#pragma unroll
    for (int rep = 0; rep < 4; rep++) {
      int gi = rep * 256 + tid;  // l2(4b) qd(2b) nf2(2b) esp(1b) kt2(1b)
      int l2 = gi & 15, qd = (gi >> 4) & 3, nf2 = (gi >> 6) & 3,
          esp = (gi >> 8) & 1, kt2 = (gi >> 9) & 1;
      int tl = kt2 * 64 + nf2 * 16 + l2;
      bf16x8 val = *(const bf16x8*)&tp[tl * 72 + esp * 32 + qd * 8];
      int kt = (mtb * 2 + kt2) & 31;
      int es = c * 2 + esp;
      size_t off = (((size_t)((bhx * 32 + kt) * 24) + es * 4 + nf2) * 64 +
                    (size_t)(qd * 16 + l2)) * 8;
      *(bf16x8*)(dst + off) = val;
    }
  } else {
#pragma unroll
    for (int i = 0; i < 4; i++) {
      int kt = (mtb * 2 + wm) & 31;
      int ks2 = (i >> 1) & 1;
      int qd2 = (i * 2 + (quad >> 1)) & 3;
#pragma unroll
      for (int j = 0; j < 2; j++) {
        int ef = c * 4 + wn * 2 + j;
        size_t off = ((size_t)((bhx * 32 + kt) * 24 + ks2 * 12 + ef)) * 512 +
                     (qd2 * 16 + ln) * 8 + (quad & 1) * 4;
        bf16x4 val = { f2bf(acc[i][j][0]), f2bf(acc[i][j][1]),
                       f2bf(acc[i][j][2]), f2bf(acc[i][j][3]) };
        *(bf16x4*)(vp + off) = val;
      }
    }
  }
}

// ---------------------------------------------------------------- attn
// Split-K(2), 32-key dbuf tiles, one barrier/iter (R13). NEW: QK computed as
// S^T via operand swap (mfma(kf, qf) -- A/B lane layouts identical), so the
// C-layout gives col=q-row, row=key: each lane holds 4 CONSECUTIVE keys of
// one q-row -> P store is ds_write_b64 (4/iter vs 16 b16); l is a per-lane
// scalar per rg (2-shuffle final reduce). P-read/V/acc/epilogue unchanged.
__global__ __launch_bounds__(256, 2) void attn(const short* __restrict__ qp,
                                               const short* __restrict__ kp,
                                               const short* __restrict__ vp,
                                               short* __restrict__ opart,
                                               float* __restrict__ lpart) {
  __shared__ __align__(16) short pool[29696];  // K[2]x6144 | V[2]x6144 | P 8*16*40
  int pair = blockIdx.x, qt = blockIdx.y;
  int bh = pair & 15, kh = pair >> 4;
  int tid = threadIdx.x, wave = tid >> 6, lane = tid & 63;
  int ln = lane & 15, quad = lane >> 4;
  short* Pl = pool + 24576;

  bf16x8 qf[2][6];
#pragma unroll
  for (int rg = 0; rg < 2; rg++) {
    int fi = wave * 2 + rg;
    const short* qb = qp +
        ((size_t)(bh * 32 + qt * 2 + (fi >> 2)) * 24 + (fi & 3)) * 512 + lane * 8;
#pragma unroll
    for (int es = 0; es < 6; es++) qf[rg][es] = *(const bf16x8*)(qb + es * 2048);
  }

  float l_r[2] = {0.f, 0.f};
  f32x4 acc[2][12] = {};
  const short* gKb = kp + (size_t)(bh * 32 + kh * 16) * 12288;
  const short* gVb = vp + (size_t)(bh * 32 + kh * 16) * 12288;

  auto stage = [&](int k32, int buf) {
    const short* g64K = gKb + (size_t)(k32 >> 1) * 12288;
    const short* g64V = gVb + (size_t)(k32 >> 1) * 12288;
    int half = k32 & 1;
    short* Kd = pool + buf * 6144;
    short* Vd = pool + 12288 + buf * 6144;
#pragma unroll
    for (int i = 0; i < 3; i++) {
      int q = i * 256 + tid;
      int f = q >> 6, l = q & 63;
      int es = f >> 1, nfl = f & 1;
      load_lds16(g64K + (size_t)(es * 4 + half * 2 + nfl) * 512 + l * 8, Kd + q * 8);
      load_lds16(g64V + (size_t)(half * 12 + f) * 512 + l * 8, Vd + q * 8);
    }
  };

  stage(0, 0);
  for (int kt = 0; kt < 32; kt++) {
    int b = kt & 1;
    __syncthreads();
    if (kt < 31) stage(kt + 1, b ^ 1);
    const short* Kl = pool + b * 6144;
    const short* Vl = pool + 12288 + b * 6144;

    // S^T = K Q^T (A=kf from LDS, B=qf regs): row=key(quad*4+jj), col=qrow(ln)
    f32x4 s[2][2] = {};
#pragma unroll
    for (int es = 0; es < 6; es++) {
#pragma unroll
      for (int nfl = 0; nfl < 2; nfl++) {
        bf16x8 kf = *(const bf16x8*)&Kl[(es * 2 + nfl) * 512 + lane * 8];
        s[0][nfl] = __builtin_amdgcn_mfma_f32_16x16x32_bf16(kf, qf[0][es], s[0][nfl], 0, 0, 0);
        s[1][nfl] = __builtin_amdgcn_mfma_f32_16x16x32_bf16(kf, qf[1][es], s[1][nfl], 0, 0, 0);
      }
    }

    // exp2 -> bf16x4 packed store: P[qrow=ln][key = nfl*16 + quad*4 + jj]
#pragma unroll
    for (int rg = 0; rg < 2; rg++)
#pragma unroll
      for (int nfl = 0; nfl < 2; nfl++) {
        bf16x4 pk4;
#pragma unroll
        for (int jj = 0; jj < 4; jj++) {
          float p = __builtin_amdgcn_exp2f(s[rg][nfl][jj]);
          union { float f; unsigned u; } v; v.f = p;
          pk4[jj] = (short)((v.u + 0x8000u) >> 16);
          l_r[rg] += p;
        }
        *(bf16x4*)&Pl[((wave * 2 + rg) * 16 + ln) * 40 + nfl * 16 + quad * 4] = pk4;
      }

    bf16x8 pa[2];
#pragma unroll
    for (int rg = 0; rg < 2; rg++)  // same-wave ds ordering via lgkmcnt
      pa[rg] = *(const bf16x8*)&Pl[((wave * 2 + rg) * 16 + ln) * 40 + quad * 8];

#pragma unroll
    for (int ef = 0; ef < 12; ef++) {
      bf16x8 v0 = *(const bf16x8*)&Vl[ef * 512 + lane * 8];
      acc[0][ef] = __builtin_amdgcn_mfma_f32_16x16x32_bf16(pa[0], v0, acc[0][ef], 0, 0, 0);
      acc[1][ef] = __builtin_amdgcn_mfma_f32_16x16x32_bf16(pa[1], v0, acc[1][ef], 0, 0, 0);
    }
  }

  // l reduce: sum over quads (keys were distributed across quads+nfl)
#pragma unroll
  for (int rg = 0; rg < 2; rg++) {
    l_r[rg] += __shfl_xor(l_r[rg], 16, 64);
    l_r[rg] += __shfl_xor(l_r[rg], 32, 64);
  }

  __syncthreads();
  short* tp = pool;  // [128][200] = 25600 <= 29696
#pragma unroll
  for (int rg = 0; rg < 2; rg++)
#pragma unroll
    for (int jj = 0; jj < 4; jj++) {
      int row = (wave * 2 + rg) * 16 + quad * 4 + jj;
#pragma unroll
      for (int ef = 0; ef < 12; ef++)
        tp[row * 200 + ef * 16 + ln] = f2bf(acc[rg][ef][jj]);
    }
  __syncthreads();
  const size_t obase = ((size_t)(kh * 16 + bh) * 2048 + qt * 128) * 192;
#pragma unroll
  for (int rep = 0; rep < 12; rep++) {
    int gi = rep * 256 + tid;
    int row = gi / 24, c8 = gi - row * 24;
    *(bf16x8*)(opart + obase + (size_t)row * 192 + c8 * 8) =
        *(const bf16x8*)&tp[row * 200 + c8 * 8];
  }
  int lb = (kh * 16 + bh) * 2048 + qt * 128;
  if (quad == 0) {
#pragma unroll
    for (int rg = 0; rg < 2; rg++)
      lpart[lb + (wave * 2 + rg) * 16 + ln] = l_r[rg];
  }
}

// ---------------------------------------------------------------- out_gemm v4
// (R14-proven) c-FUSED merge + projection; grid 256; coalesced fp32 output.
__global__ __launch_bounds__(256) void out_gemm(const short* __restrict__ opart,
                                                const float* __restrict__ lpart,
                                                const short* __restrict__ wop,
                                                float* __restrict__ out) {
  __shared__ __align__(16) float pool_f[12352];  // 49408 B
  short* Al = (short*)pool_f;                    // [3][16 ks][512]
  int mtb = blockIdx.x;
  int tid = threadIdx.x, wave = tid >> 6, lane = tid & 63;
  int ln = lane & 15, quad = lane >> 4;
  const size_t HSTR = (size_t)16 * 2048 * 192;

#pragma unroll
  for (int rep = 0; rep < 12; rep++) {
    int g = rep * 256 + tid;
    int c = g >> 10, inner = g & 1023;
    int d8 = inner & 7, h = (inner >> 3) & 7, row16 = inner >> 6;
    int t = mtb * 16 + row16, b = t >> 11, n = t & 2047;
    int bh = b * 8 + h;
    size_t src = ((size_t)bh * 2048 + n) * 192 + c * 64 + d8 * 8;
    bf16x8 o1 = *(const bf16x8*)(opart + src);
    bf16x8 o2 = *(const bf16x8*)(opart + HSTR + src);
    float l = lpart[bh * 2048 + n] + lpart[32768 + bh * 2048 + n];
    float inv = 1.f / l;
    bf16x8 r;
#pragma unroll
    for (int j = 0; j < 8; j++) r[j] = f2bf((bf2f(o1[j]) + bf2f(o2[j])) * inv);
    int ks = h * 2 + (d8 >> 2), qd = d8 & 3;
    *(bf16x8*)&Al[c * 8192 + ks * 512 + (qd * 16 + row16) * 8] = r;
  }
  __syncthreads();

  f32x4 acc[3][4] = {};
  for (int ks = 0; ks < 16; ks++) {
    bf16x8 af[3];
#pragma unroll
    for (int c = 0; c < 3; c++) af[c] = *(const bf16x8*)&Al[c * 8192 + ks * 512 + lane * 8];
#pragma unroll
    for (int jf = 0; jf < 4; jf++) {
      int nt = wave * 4 + jf;
      bf16x8 bfr = *(const bf16x8*)(wop + (size_t)(nt * 16 + ks) * 512 + lane * 8);
#pragma unroll
      for (int c = 0; c < 3; c++)
        acc[c][jf] = __builtin_amdgcn_mfma_f32_16x16x32_bf16(af[c], bfr, acc[c][jf], 0, 0, 0);
    }
  }
  __syncthreads();  // Al dead; reuse pool_f for the fp32 out-tile [16][772]
#pragma unroll
  for (int c = 0; c < 3; c++)
#pragma unroll
    for (int jf = 0; jf < 4; jf++) {
      int o2 = (wave * 4 + jf) * 16 + ln;
#pragma unroll
      for (int jj = 0; jj < 4; jj++)
        pool_f[(quad * 4 + jj) * 772 + o2 * 3 + c] = acc[c][jf][jj];
    }
  __syncthreads();
  float* ob = out + (size_t)mtb * 12288;
#pragma unroll
  for (int rep = 0; rep < 12; rep++) {
    int idx = rep * 256 + tid;
    int row = idx / 192, col4 = idx - row * 192;
    *(float4v*)(ob + row * 768 + col4 * 4) =
        *(const float4v*)(pool_f + row * 772 + col4 * 4);
  }
}

// ---------------------------------------------------------------- launch
extern "C" void kernel_launch(void* const* d_in, const int* in_sizes, int n_in,
                              void* d_out, int out_size, void* d_ws, size_t ws_size,
                              hipStream_t stream) {
  const float* x  = (const float*)d_in[0];
  const float* Wq = (const float*)d_in[1];
  const float* Wk = (const float*)d_in[2];
  const float* Wv = (const float*)d_in[3];
  const float* Wo = (const float*)d_in[4];
  float* out = (float*)d_out;

  short* ws    = (short*)d_ws;
  short* xcp   = ws;                                   // 3*4096*256
  short* wqkvp = xcp + 3 * NTOK * CIN;                 // 1536*256
  short* wop   = wqkvp + 1536 * 256;                   // 256*512
  short* qp    = wop + 256 * 512;                      // 16*2048*192
  short* kp    = qp + (size_t)BHTOT * NSEQ * E;
  short* vp    = kp + (size_t)BHTOT * NSEQ * E;
  short* opart = vp + (size_t)BHTOT * NSEQ * E;        // 2*16*2048*192
  float* lpart = (float*)xcp;   // ALIAS: xcp dead after qkv_gemm (stream order)

  prep<<<2304, 256, 0, stream>>>(x, Wq, Wk, Wv, Wo, xcp, wqkvp, wop);
  qkv_gemm<<<dim3(24, 32, 3), 256, 0, stream>>>(xcp, wqkvp, qp, kp, vp);
  attn<<<dim3(32, 16), 256, 0, stream>>>(qp, kp, vp, opart, lpart);
  out_gemm<<<256, 256, 0, stream>>>(opart, lpart, wop, out);
}

// Round 16
// 157.821 us; speedup vs baseline: 1.0134x; 1.0134x over previous
//
#include <hip/hip_runtime.h>

#define HEADS 8
#define DH 64
#define CO 3
#define E 192
#define NSEQ 2048
#define BATCH 2
#define CIN 256
#define DINNER 512
#define NTOK 4096
#define BHTOT 16

typedef __attribute__((ext_vector_type(8))) short bf16x8;
typedef __attribute__((ext_vector_type(4))) short bf16x4;
typedef __attribute__((ext_vector_type(4))) float f32x4;
typedef __attribute__((ext_vector_type(4))) float float4v;

static __device__ inline short f2bf(float f) {
  union { float f; unsigned u; } v; v.f = f;
  unsigned r = (v.u + 0x7FFFu + ((v.u >> 16) & 1u)) >> 16;  // RNE
  return (short)r;
}

static __device__ inline float bf2f(short s) {
  union { unsigned u; float f; } a;
  a.u = ((unsigned)(unsigned short)s) << 16;
  return a.f;
}

static __device__ inline void load_lds16(const short* g, short* l) {
  __builtin_amdgcn_global_load_lds(
      (const __attribute__((address_space(1))) void*)g,
      (__attribute__((address_space(3))) void*)l, 16, 0, 0);
}

// Frag-tile packing: a 16(row)x32(k) bf16 MFMA operand tile = 512 shorts,
// element [row r][k = qd*8+j] at (qd*16 + r)*8 + j (consuming wave's lane order).
// Internal e-order: e = c*64 + d.

// ---------------------------------------------------------------- prep
__global__ __launch_bounds__(256) void prep(const float* __restrict__ x,
                                            const float* __restrict__ Wq,
                                            const float* __restrict__ Wk,
                                            const float* __restrict__ Wv,
                                            const float* __restrict__ Wo,
                                            short* __restrict__ xcp,
                                            short* __restrict__ wqkvp,
                                            short* __restrict__ wop) {
  int tid = threadIdx.x;
  if (blockIdx.x < 256) {
    __shared__ short st[12288];  // [c][ks][512]
    int mt = blockIdx.x;
    const float* xb = x + (size_t)mt * 12288;
#pragma unroll
    for (int r = 0; r < 12; r++) {
      int idx4 = r * 256 + tid;
      float4v v = *(const float4v*)(xb + idx4 * 4);
#pragma unroll
      for (int e = 0; e < 4; e++) {
        int fp = idx4 * 4 + e;
        int ti = fp / 3, c = fp - ti * 3;
        int tl = ti >> 8, i = ti & 255;
        int ks = i >> 5, qd = (i >> 3) & 3, j = i & 7;
        st[c * 4096 + ks * 512 + (qd * 16 + tl) * 8 + j] = f2bf(v[e]);
      }
    }
    __syncthreads();
    short* dst = xcp;
#pragma unroll
    for (int rep = 0; rep < 6; rep++) {
      int g = rep * 256 + tid;
      int c = g >> 9, rem = g & 511;
      *(bf16x8*)(dst + ((size_t)(c * 256 + mt) * 8) * 512 + rem * 8) =
          *(const bf16x8*)&st[c * 4096 + rem * 8];
    }
    return;
  }
  int idx = (blockIdx.x - 256) * 256 + tid;
  const float qscale = 0.07216878364870323f * 1.4426950408889634f;  // 192^-0.5 * log2(e)
  if (idx < 1536 * 256) {
    int o = idx >> 8, i = idx & 255;
    float v;
    if (o < 512) v = Wq[idx] * qscale;
    else if (o < 1024) v = Wk[idx - 512 * 256];
    else v = Wv[idx - 1024 * 256];
    int nt = o >> 4, ln = o & 15, ks = i >> 5, qd = (i >> 3) & 3, j = i & 7;
    wqkvp[((size_t)(nt * 8 + ks)) * 512 + (qd * 16 + ln) * 8 + j] = f2bf(v);
  } else {
    int j0 = idx - 1536 * 256;
    if (j0 < 256 * 512) {
      int o2 = j0 >> 9, i = j0 & 511;
      int nt = o2 >> 4, ln = o2 & 15, ks = i >> 5, qd = (i >> 3) & 3, j = i & 7;
      wop[((size_t)(nt * 16 + ks)) * 512 + (qd * 16 + ln) * 8 + j] = f2bf(Wo[j0]);
    }
  }
}

// ---------------------------------------------------------------- qkv_gemm v3
// (R14-proven; v4's 2-step unroll regressed — reverted.) 128m x 64n tiles,
// grid (24,32,3). mat/h uniform per block. B-frags direct from L2-resident
// wqkvp; A staged 8 KB/iter double-buffered. LDS 9.2 KB -> 4 blocks/CU.
__global__ __launch_bounds__(256, 4) void qkv_gemm(const short* __restrict__ xcp,
                                                   const short* __restrict__ wqkvp,
                                                   short* __restrict__ qp,
                                                   short* __restrict__ kp,
                                                   short* __restrict__ vp) {
  __shared__ __align__(16) short pool[9216];  // A dbuf 2x4096 | epilogue tp [128][72]
  int c = blockIdx.z, ntb = blockIdx.x, mtb = blockIdx.y;
  int tid = threadIdx.x, wave = tid >> 6, lane = tid & 63;
  int ln = lane & 15, quad = lane >> 4;
  int wm = wave >> 1, wn = wave & 1;

  const short* gA = xcp + ((size_t)(c * 256 + mtb * 8) * 8) * 512;

  f32x4 acc[4][2] = {};
#pragma unroll
  for (int i = 0; i < 2; i++) {
    int q = tid + 256 * i, mf = q >> 6, l = q & 63;
    load_lds16(gA + (size_t)(mf * 8) * 512 + l * 8, pool + q * 8);
  }
  for (int ks = 0; ks < 8; ks++) {
    int b = ks & 1;
    __syncthreads();
    if (ks < 7) {
#pragma unroll
      for (int i = 0; i < 2; i++) {
        int q = tid + 256 * i, mf = q >> 6, l = q & 63;
        load_lds16(gA + (size_t)(mf * 8 + ks + 1) * 512 + l * 8,
                   pool + (b ^ 1) * 4096 + q * 8);
      }
    }
    const short* As = pool + b * 4096;
    bf16x8 af[4], bfr[2];
#pragma unroll
    for (int j = 0; j < 2; j++)
      bfr[j] = *(const bf16x8*)(wqkvp +
          (size_t)((ntb * 4 + wn * 2 + j) * 8 + ks) * 512 + lane * 8);
#pragma unroll
    for (int i = 0; i < 4; i++) af[i] = *(const bf16x8*)&As[(wm * 4 + i) * 512 + lane * 8];
#pragma unroll
    for (int i = 0; i < 4; i++)
#pragma unroll
      for (int j = 0; j < 2; j++)
        acc[i][j] = __builtin_amdgcn_mfma_f32_16x16x32_bf16(af[i], bfr[j], acc[i][j], 0, 0, 0);
  }

  int mat = ntb >> 3;        // 0=Q 1=K 2=V (block-uniform)
  int h = ntb & 7;
  int b0 = mtb >> 4;
  int bhx = b0 * 8 + h;
  if (mat < 2) {
    __syncthreads();
    short* tp = pool;  // [128][72]: 9216 shorts; stride 72 = 36 dw (4 mod 32)
#pragma unroll
    for (int i = 0; i < 4; i++)
#pragma unroll
      for (int j = 0; j < 2; j++)
#pragma unroll
        for (int jj = 0; jj < 4; jj++)
          tp[(wm * 64 + i * 16 + quad * 4 + jj) * 72 + wn * 32 + j * 16 + ln] =
              f2bf(acc[i][j][jj]);
    __syncthreads();
    short* dst = (mat == 0) ? qp : kp;
#pragma unroll
    for (int rep = 0; rep < 4; rep++) {
      int gi = rep * 256 + tid;  // l2(4b) qd(2b) nf2(2b) esp(1b) kt2(1b)
      int l2 = gi & 15, qd = (gi >> 4) & 3, nf2 = (gi >> 6) & 3,
          esp = (gi >> 8) & 1, kt2 = (gi >> 9) & 1;
      int tl = kt2 * 64 + nf2 * 16 + l2;
      bf16x8 val = *(const bf16x8*)&tp[tl * 72 + esp * 32 + qd * 8];
      int kt = (mtb * 2 + kt2) & 31;
      int es = c * 2 + esp;
      size_t off = (((size_t)((bhx * 32 + kt) * 24) + es * 4 + nf2) * 64 +
                    (size_t)(qd * 16 + l2)) * 8;
      *(bf16x8*)(dst + off) = val;
    }
  } else {
#pragma unroll
    for (int i = 0; i < 4; i++) {
      int kt = (mtb * 2 + wm) & 31;
      int ks2 = (i >> 1) & 1;
      int qd2 = (i * 2 + (quad >> 1)) & 3;
#pragma unroll
      for (int j = 0; j < 2; j++) {
        int ef = c * 4 + wn * 2 + j;   // d = wn*32+j*16+ln -> d>>4 = wn*2+j
        size_t off = ((size_t)((bhx * 32 + kt) * 24 + ks2 * 12 + ef)) * 512 +
                     (qd2 * 16 + ln) * 8 + (quad & 1) * 4;
        bf16x4 val = { f2bf(acc[i][j][0]), f2bf(acc[i][j][1]),
                       f2bf(acc[i][j][2]), f2bf(acc[i][j][3]) };
        *(bf16x4*)(vp + off) = val;
      }
    }
  }
}

// ---------------------------------------------------------------- attn
// (R15-proven) Split-K(2), 32-key dbuf tiles, one barrier/iter, S^T operand
// swap: lane holds 4 consecutive keys of one q-row -> b64 P-stores, scalar l.
__global__ __launch_bounds__(256, 2) void attn(const short* __restrict__ qp,
                                               const short* __restrict__ kp,
                                               const short* __restrict__ vp,
                                               short* __restrict__ opart,
                                               float* __restrict__ lpart) {
  __shared__ __align__(16) short pool[29696];  // K[2]x6144 | V[2]x6144 | P 8*16*40
  int pair = blockIdx.x, qt = blockIdx.y;
  int bh = pair & 15, kh = pair >> 4;
  int tid = threadIdx.x, wave = tid >> 6, lane = tid & 63;
  int ln = lane & 15, quad = lane >> 4;
  short* Pl = pool + 24576;

  bf16x8 qf[2][6];
#pragma unroll
  for (int rg = 0; rg < 2; rg++) {
    int fi = wave * 2 + rg;
    const short* qb = qp +
        ((size_t)(bh * 32 + qt * 2 + (fi >> 2)) * 24 + (fi & 3)) * 512 + lane * 8;
#pragma unroll
    for (int es = 0; es < 6; es++) qf[rg][es] = *(const bf16x8*)(qb + es * 2048);
  }

  float l_r[2] = {0.f, 0.f};
  f32x4 acc[2][12] = {};
  const short* gKb = kp + (size_t)(bh * 32 + kh * 16) * 12288;
  const short* gVb = vp + (size_t)(bh * 32 + kh * 16) * 12288;

  auto stage = [&](int k32, int buf) {
    const short* g64K = gKb + (size_t)(k32 >> 1) * 12288;
    const short* g64V = gVb + (size_t)(k32 >> 1) * 12288;
    int half = k32 & 1;
    short* Kd = pool + buf * 6144;
    short* Vd = pool + 12288 + buf * 6144;
#pragma unroll
    for (int i = 0; i < 3; i++) {
      int q = i * 256 + tid;
      int f = q >> 6, l = q & 63;
      int es = f >> 1, nfl = f & 1;
      load_lds16(g64K + (size_t)(es * 4 + half * 2 + nfl) * 512 + l * 8, Kd + q * 8);
      load_lds16(g64V + (size_t)(half * 12 + f) * 512 + l * 8, Vd + q * 8);
    }
  };

  stage(0, 0);
  for (int kt = 0; kt < 32; kt++) {
    int b = kt & 1;
    __syncthreads();
    if (kt < 31) stage(kt + 1, b ^ 1);
    const short* Kl = pool + b * 6144;
    const short* Vl = pool + 12288 + b * 6144;

    // S^T = K Q^T: row=key(quad*4+jj), col=qrow(ln)
    f32x4 s[2][2] = {};
#pragma unroll
    for (int es = 0; es < 6; es++) {
#pragma unroll
      for (int nfl = 0; nfl < 2; nfl++) {
        bf16x8 kf = *(const bf16x8*)&Kl[(es * 2 + nfl) * 512 + lane * 8];
        s[0][nfl] = __builtin_amdgcn_mfma_f32_16x16x32_bf16(kf, qf[0][es], s[0][nfl], 0, 0, 0);
        s[1][nfl] = __builtin_amdgcn_mfma_f32_16x16x32_bf16(kf, qf[1][es], s[1][nfl], 0, 0, 0);
      }
    }

    // exp2 -> bf16x4 packed store: P[qrow=ln][key = nfl*16 + quad*4 + jj]
#pragma unroll
    for (int rg = 0; rg < 2; rg++)
#pragma unroll
      for (int nfl = 0; nfl < 2; nfl++) {
        bf16x4 pk4;
#pragma unroll
        for (int jj = 0; jj < 4; jj++) {
          float p = __builtin_amdgcn_exp2f(s[rg][nfl][jj]);
          union { float f; unsigned u; } v; v.f = p;
          pk4[jj] = (short)((v.u + 0x8000u) >> 16);
          l_r[rg] += p;
        }
        *(bf16x4*)&Pl[((wave * 2 + rg) * 16 + ln) * 40 + nfl * 16 + quad * 4] = pk4;
      }

    bf16x8 pa[2];
#pragma unroll
    for (int rg = 0; rg < 2; rg++)  // same-wave ds ordering via lgkmcnt
      pa[rg] = *(const bf16x8*)&Pl[((wave * 2 + rg) * 16 + ln) * 40 + quad * 8];

#pragma unroll
    for (int ef = 0; ef < 12; ef++) {
      bf16x8 v0 = *(const bf16x8*)&Vl[ef * 512 + lane * 8];
      acc[0][ef] = __builtin_amdgcn_mfma_f32_16x16x32_bf16(pa[0], v0, acc[0][ef], 0, 0, 0);
      acc[1][ef] = __builtin_amdgcn_mfma_f32_16x16x32_bf16(pa[1], v0, acc[1][ef], 0, 0, 0);
    }
  }

  // l reduce: keys were distributed across quads (and nfl, already summed)
#pragma unroll
  for (int rg = 0; rg < 2; rg++) {
    l_r[rg] += __shfl_xor(l_r[rg], 16, 64);
    l_r[rg] += __shfl_xor(l_r[rg], 32, 64);
  }

  __syncthreads();
  short* tp = pool;  // [128][200] = 25600 <= 29696
#pragma unroll
  for (int rg = 0; rg < 2; rg++)
#pragma unroll
    for (int jj = 0; jj < 4; jj++) {
      int row = (wave * 2 + rg) * 16 + quad * 4 + jj;
#pragma unroll
      for (int ef = 0; ef < 12; ef++)
        tp[row * 200 + ef * 16 + ln] = f2bf(acc[rg][ef][jj]);
    }
  __syncthreads();
  const size_t obase = ((size_t)(kh * 16 + bh) * 2048 + qt * 128) * 192;
#pragma unroll
  for (int rep = 0; rep < 12; rep++) {
    int gi = rep * 256 + tid;
    int row = gi / 24, c8 = gi - row * 24;
    *(bf16x8*)(opart + obase + (size_t)row * 192 + c8 * 8) =
        *(const bf16x8*)&tp[row * 200 + c8 * 8];
  }
  int lb = (kh * 16 + bh) * 2048 + qt * 128;
  if (quad == 0) {
#pragma unroll
    for (int rg = 0; rg < 2; rg++)
      lpart[lb + (wave * 2 + rg) * 16 + ln] = l_r[rg];
  }
}

// ---------------------------------------------------------------- out_gemm v4
// (R14-proven) c-FUSED merge + projection; grid 256; coalesced fp32 output.
__global__ __launch_bounds__(256) void out_gemm(const short* __restrict__ opart,
                                                const float* __restrict__ lpart,
                                                const short* __restrict__ wop,
                                                float* __restrict__ out) {
  __shared__ __align__(16) float pool_f[12352];  // 49408 B
  short* Al = (short*)pool_f;                    // [3][16 ks][512]
  int mtb = blockIdx.x;
  int tid = threadIdx.x, wave = tid >> 6, lane = tid & 63;
  int ln = lane & 15, quad = lane >> 4;
  const size_t HSTR = (size_t)16 * 2048 * 192;

#pragma unroll
  for (int rep = 0; rep < 12; rep++) {
    int g = rep * 256 + tid;
    int c = g >> 10, inner = g & 1023;
    int d8 = inner & 7, h = (inner >> 3) & 7, row16 = inner >> 6;
    int t = mtb * 16 + row16, b = t >> 11, n = t & 2047;
    int bh = b * 8 + h;
    size_t src = ((size_t)bh * 2048 + n) * 192 + c * 64 + d8 * 8;
    bf16x8 o1 = *(const bf16x8*)(opart + src);
    bf16x8 o2 = *(const bf16x8*)(opart + HSTR + src);
    float l = lpart[bh * 2048 + n] + lpart[32768 + bh * 2048 + n];
    float inv = 1.f / l;
    bf16x8 r;
#pragma unroll
    for (int j = 0; j < 8; j++) r[j] = f2bf((bf2f(o1[j]) + bf2f(o2[j])) * inv);
    int ks = h * 2 + (d8 >> 2), qd = d8 & 3;
    *(bf16x8*)&Al[c * 8192 + ks * 512 + (qd * 16 + row16) * 8] = r;
  }
  __syncthreads();

  f32x4 acc[3][4] = {};
  for (int ks = 0; ks < 16; ks++) {
    bf16x8 af[3];
#pragma unroll
    for (int c = 0; c < 3; c++) af[c] = *(const bf16x8*)&Al[c * 8192 + ks * 512 + lane * 8];
#pragma unroll
    for (int jf = 0; jf < 4; jf++) {
      int nt = wave * 4 + jf;
      bf16x8 bfr = *(const bf16x8*)(wop + (size_t)(nt * 16 + ks) * 512 + lane * 8);
#pragma unroll
      for (int c = 0; c < 3; c++)
        acc[c][jf] = __builtin_amdgcn_mfma_f32_16x16x32_bf16(af[c], bfr, acc[c][jf], 0, 0, 0);
    }
  }
  __syncthreads();  // Al dead; reuse pool_f for the fp32 out-tile [16][772]
#pragma unroll
  for (int c = 0; c < 3; c++)
#pragma unroll
    for (int jf = 0; jf < 4; jf++) {
      int o2 = (wave * 4 + jf) * 16 + ln;
#pragma unroll
      for (int jj = 0; jj < 4; jj++)
        pool_f[(quad * 4 + jj) * 772 + o2 * 3 + c] = acc[c][jf][jj];
    }
  __syncthreads();
  float* ob = out + (size_t)mtb * 12288;
#pragma unroll
  for (int rep = 0; rep < 12; rep++) {
    int idx = rep * 256 + tid;
    int row = idx / 192, col4 = idx - row * 192;
    *(float4v*)(ob + row * 768 + col4 * 4) =
        *(const float4v*)(pool_f + row * 772 + col4 * 4);
  }
}

// ---------------------------------------------------------------- launch
extern "C" void kernel_launch(void* const* d_in, const int* in_sizes, int n_in,
                              void* d_out, int out_size, void* d_ws, size_t ws_size,
                              hipStream_t stream) {
  const float* x  = (const float*)d_in[0];
  const float* Wq = (const float*)d_in[1];
  const float* Wk = (const float*)d_in[2];
  const float* Wv = (const float*)d_in[3];
  const float* Wo = (const float*)d_in[4];
  float* out = (float*)d_out;

  short* ws    = (short*)d_ws;
  short* xcp   = ws;                                   // 3*4096*256
  short* wqkvp = xcp + 3 * NTOK * CIN;                 // 1536*256
  short* wop   = wqkvp + 1536 * 256;                   // 256*512
  short* qp    = wop + 256 * 512;                      // 16*2048*192
  short* kp    = qp + (size_t)BHTOT * NSEQ * E;
  short* vp    = kp + (size_t)BHTOT * NSEQ * E;
  short* opart = vp + (size_t)BHTOT * NSEQ * E;        // 2*16*2048*192
  float* lpart = (float*)xcp;   // ALIAS: xcp dead after qkv_gemm (stream order)

  prep<<<2304, 256, 0, stream>>>(x, Wq, Wk, Wv, Wo, xcp, wqkvp, wop);
  qkv_gemm<<<dim3(24, 32, 3), 256, 0, stream>>>(xcp, wqkvp, qp, kp, vp);
  attn<<<dim3(32, 16), 256, 0, stream>>>(qp, kp, vp, opart, lpart);
  out_gemm<<<256, 256, 0, stream>>>(opart, lpart, wop, out);
}